// Round 4
// baseline (1644.852 us; speedup 1.0000x reference)
//
#include <hip/hip_runtime.h>

typedef _Float16 f16;
typedef _Float16 h2 __attribute__((ext_vector_type(2)));
typedef _Float16 h8 __attribute__((ext_vector_type(8)));
typedef float    f4 __attribute__((ext_vector_type(4)));

#define S_  256
#define B_  1024
#define D_  64
#define H_  128
#define Z_  32
#define BD_ (B_*D_)
#define NSTEP 514

__device__ __forceinline__ float fdot2(h2 a, h2 b, float c) {
#if __has_builtin(__builtin_amdgcn_fdot2)
  return __builtin_amdgcn_fdot2(a, b, c, false);
#else
  return c + (float)a[0]*(float)b[0] + (float)a[1]*(float)b[1];
#endif
}

__device__ __forceinline__ float dot8(h8 a, h8 w, float acc) {
  h2 a0 = __builtin_shufflevector(a, a, 0, 1), w0 = __builtin_shufflevector(w, w, 0, 1);
  h2 a1 = __builtin_shufflevector(a, a, 2, 3), w1 = __builtin_shufflevector(w, w, 2, 3);
  h2 a2 = __builtin_shufflevector(a, a, 4, 5), w2 = __builtin_shufflevector(w, w, 4, 5);
  h2 a3 = __builtin_shufflevector(a, a, 6, 7), w3 = __builtin_shufflevector(w, w, 6, 7);
  acc = fdot2(a0, w0, acc);
  acc = fdot2(a1, w1, acc);
  acc = fdot2(a2, w2, acc);
  acc = fdot2(a3, w3, acc);
  return acc;
}

__device__ __forceinline__ h8 ld8(const float* p) {   // 32B-aligned src
  f4 a = *(const f4*)p;
  f4 b = *(const f4*)(p + 4);
  h8 w;
  w[0]=(f16)a[0]; w[1]=(f16)a[1]; w[2]=(f16)a[2]; w[3]=(f16)a[3];
  w[4]=(f16)b[0]; w[5]=(f16)b[1]; w[6]=(f16)b[2]; w[7]=(f16)b[3];
  return w;
}

__device__ __forceinline__ float sigm(float x) { return 1.f / (1.f + __expf(-x)); }
__device__ __forceinline__ float tanh_(float x) {
  float e = __expf(-2.f * fabsf(x));
  float t = (1.f - e) / (1.f + e);
  return copysignf(t, x);
}

// ---------------------------------------------------------------------------
// GRU: round-0 structure (best measured: ~628us). UNCHANGED this round.
// ---------------------------------------------------------------------------
__global__ __launch_bounds__(256, 2) void gru_kernel(
    const float* __restrict__ xs, const float* __restrict__ Wih,
    const float* __restrict__ Whh, const float* __restrict__ bih,
    const float* __restrict__ bhh, float* __restrict__ hT)
{
  __shared__ h8 actH[16][2];               // h f16 [chunk][b]
  __shared__ h8 xv[8][2];                  // x f16 [chunk][b]
  __shared__ float part[2][2][4][128];     // [kh][b][r,z,nh,nx][jh]

  const int t  = threadIdx.x;
  const int b0 = blockIdx.x * 2;
  const int jh = t & 127;
  const int kh = t >> 7;

  h8 whr[8], whz[8], whn[8], wxr[4], wxz[4], wxn[4];
  {
    const float* pr = Whh + jh*H_        + kh*64;
    const float* pz = Whh + (jh+128)*H_  + kh*64;
    const float* pn = Whh + (jh+256)*H_  + kh*64;
    #pragma unroll
    for (int c = 0; c < 8; ++c) {
      whr[c] = ld8(pr + c*8);
      whz[c] = ld8(pz + c*8);
      whn[c] = ld8(pn + c*8);
    }
    const float* qr = Wih + jh*D_        + kh*32;
    const float* qz = Wih + (jh+128)*D_  + kh*32;
    const float* qn = Wih + (jh+256)*D_  + kh*32;
    #pragma unroll
    for (int c = 0; c < 4; ++c) {
      wxr[c] = ld8(qr + c*8);
      wxz[c] = ld8(qz + c*8);
      wxn[c] = ld8(qn + c*8);
    }
  }
  const int gb = t >> 7, hd = t & 127;     // gate-phase role
  const float bir = bih[hd], biz = bih[hd+128], bin = bih[hd+256];
  const float bhr = bhh[hd], bhz = bhh[hd+128], bhn = bhh[hd+256];
  float hmast = 0.f;

  if (t < 32) { h8 zz = {}; actH[t>>1][t&1] = zz; }
  if (t < 128) {
    int b = t >> 6, d = t & 63;
    float x0 = xs[(S_-1)*BD_ + (b0+b)*D_ + d];
    ((f16*)xv)[((d>>3)*2 + b)*8 + (d&7)] = (f16)x0;
  }
  __syncthreads();

  #pragma unroll 1
  for (int s = 0; s < S_; ++s) {
    float xnext = 0.f;
    if (s < S_-1 && t < 128) {
      int b = t >> 6, d = t & 63;
      xnext = xs[(S_-2-s)*BD_ + (b0+b)*D_ + d];
    }
    // partial dots, 8 independent chains (2 batches x {r,z,nh,(nx)})
    float pr0=0.f, pz0=0.f, pnh0=0.f, pnx0=0.f;
    float pr1=0.f, pz1=0.f, pnh1=0.f, pnx1=0.f;
    #pragma unroll
    for (int c = 0; c < 8; ++c) {
      h8 a0 = actH[kh*8 + c][0];
      h8 a1 = actH[kh*8 + c][1];
      pr0  = dot8(a0, whr[c], pr0);   pr1  = dot8(a1, whr[c], pr1);
      pz0  = dot8(a0, whz[c], pz0);   pz1  = dot8(a1, whz[c], pz1);
      pnh0 = dot8(a0, whn[c], pnh0);  pnh1 = dot8(a1, whn[c], pnh1);
    }
    #pragma unroll
    for (int c = 0; c < 4; ++c) {
      h8 a0 = xv[kh*4 + c][0];
      h8 a1 = xv[kh*4 + c][1];
      pr0  = dot8(a0, wxr[c], pr0);   pr1  = dot8(a1, wxr[c], pr1);
      pz0  = dot8(a0, wxz[c], pz0);   pz1  = dot8(a1, wxz[c], pz1);
      pnx0 = dot8(a0, wxn[c], pnx0);  pnx1 = dot8(a1, wxn[c], pnx1);
    }
    part[kh][0][0][jh] = pr0;   part[kh][1][0][jh] = pr1;
    part[kh][0][1][jh] = pz0;   part[kh][1][1][jh] = pz1;
    part[kh][0][2][jh] = pnh0;  part[kh][1][2][jh] = pnh1;
    part[kh][0][3][jh] = pnx0;  part[kh][1][3][jh] = pnx1;
    __syncthreads();

    // gate math: thread (gb, hd) owns h[gb][hd] master fp32
    {
      float pr  = part[0][gb][0][hd] + part[1][gb][0][hd];
      float pz  = part[0][gb][1][hd] + part[1][gb][1][hd];
      float pnh = part[0][gb][2][hd] + part[1][gb][2][hd];
      float pnx = part[0][gb][3][hd] + part[1][gb][3][hd];
      float r  = sigm(pr + bir + bhr);
      float zg = sigm(pz + biz + bhz);
      float n  = tanh_(pnx + bin + r*(pnh + bhn));
      hmast = (1.f - zg)*n + zg*hmast;
      ((f16*)actH)[((hd>>3)*2 + gb)*8 + (hd&7)] = (f16)hmast;
    }
    if (s < S_-1 && t < 128) {
      int b = t >> 6, d = t & 63;
      ((f16*)xv)[((d>>3)*2 + b)*8 + (d&7)] = (f16)xnext;
    }
    __syncthreads();
  }
  hT[(b0 + gb)*H_ + hd] = hmast;
}

// ---------------------------------------------------------------------------
// Encoder head (unchanged; tiny): 256 blocks x 4 rows.
// ---------------------------------------------------------------------------
__global__ __launch_bounds__(256) void enc_kernel(
    const float* __restrict__ hT, const float* __restrict__ encW,
    const float* __restrict__ encB, const float* __restrict__ qW,
    const float* __restrict__ qB, const float* __restrict__ eps,
    const float* __restrict__ pm, const float* __restrict__ pls,
    float* __restrict__ z0, float* __restrict__ out)
{
  __shared__ float hTl[4][128];
  __shared__ float ctx[4][64];
  __shared__ float ql[4][64];
  const int t = threadIdx.x;
  const int b0 = blockIdx.x * 4;
  const int lb = t >> 6, j = t & 63;

  for (int i = t; i < 512; i += 256) hTl[i>>7][i&127] = hT[b0*H_ + i];
  __syncthreads();

  float acc = encB[j];
  #pragma unroll
  for (int k = 0; k < 128; k += 4) {
    f4 w = *(const f4*)&encW[j*128 + k];
    acc += hTl[lb][k]*w[0] + hTl[lb][k+1]*w[1] + hTl[lb][k+2]*w[2] + hTl[lb][k+3]*w[3];
  }
  ctx[lb][j] = acc;
  __syncthreads();

  float q = qB[j];
  #pragma unroll
  for (int k = 0; k < 64; k += 4) {
    f4 w = *(const f4*)&qW[j*64 + k];
    q += ctx[lb][k]*w[0] + ctx[lb][k+1]*w[1] + ctx[lb][k+2]*w[2] + ctx[lb][k+3]*w[3];
  }
  ql[lb][j] = q;
  __syncthreads();

  float kl = 0.f;
  if (j < 32) {
    float mean = ql[lb][j], ls = ql[lb][j+32];
    z0[(b0+lb)*Z_ + j] = mean + __expf(ls)*eps[(b0+lb)*Z_ + j];
    float pmj = pm[j], plsj = pls[j];
    float dm = mean - pmj;
    kl = plsj - ls + (__expf(2.f*ls) + dm*dm) / (2.f*__expf(2.f*plsj)) - 0.5f;
  }
  #pragma unroll
  for (int s2 = 32; s2 > 0; s2 >>= 1) kl += __shfl_down(kl, s2, 64);
  if (j == 0) atomicAdd(out + 1, kl * (1.f/1024.f));
}

// ---------------------------------------------------------------------------
// SDE round-4: 512 blocks x 2 batch rows, 512 threads (8 waves), (512,4).
// Same 16 waves/CU as before, but per-thread WEIGHT registers halve
// (~80 -> ~40 h8 regs: weights shared across the 2 batch rows) -> total
// demand ~90 < 128 unified -> no AGPR shuffle traffic (the ~30% VALU tax
// diagnosed from VGPR_Count=64 + 256 inst/thread/step at round 3).
// Roles (all reductions in-wave over adjacent lanes):
//   P1: r1=t>>1 (256 rows of [fW1;gW1]), k1=t&1  (z half, 2 h8 w)
//   P2: j2=t>>2 (128 rows fW2),          kq=t&3  (k quarter, 4 h8 w)
//   P3: o3=t>>3 (64 = 32 drift+32 diff), ke=t&7  (k eighth, 2 h8 w)
//   proj: pd=t>>1 (64 rows pW, t<128),   kp=t&1  (z half, 2 h8 w)
// LDS (batch-outer, transposed slots — all reads <=2-way = free):
//   h1 slots  0..15: slot(m) = (m&3)*4 + (m>>2)   (kq lanes -> 4 adjacent lines)
//   gh slots 16..31: slot(n) = 16 + (n&1)*8 + ke  (ke lanes -> 8 bank-quads)
//   h2 slots 34..49: slot(n) = 34 + (n&1)*8 + ke  (+2 skew vs gh)
// ---------------------------------------------------------------------------
__global__ __launch_bounds__(512, 4) void sde_kernel(
    const float* __restrict__ z0, const float* __restrict__ ts,
    const float* __restrict__ dW, const float* __restrict__ xs,
    const float* __restrict__ fW1, const float* __restrict__ fb1,
    const float* __restrict__ fW2, const float* __restrict__ fb2,
    const float* __restrict__ fW3, const float* __restrict__ fb3,
    const float* __restrict__ gW1, const float* __restrict__ gb1,
    const float* __restrict__ gW2, const float* __restrict__ gb2,
    const float* __restrict__ pW, const float* __restrict__ pb,
    float* __restrict__ out)
{
  __shared__ h8 hA[2][50];       // [batch][slot]; 32,33 pad
  __shared__ h8 zcB[2][4];       // [batch] z f16 (32 values)
  __shared__ float tsL[516];
  __shared__ float lred[2];

  const int t  = threadIdx.x;
  const int b0 = blockIdx.x * 2;

  // --- P1 role ---
  const int r1 = t >> 1, k1 = t & 1;
  const float* w1src = (r1 < 128) ? (fW1 + r1*33) : (gW1 + (r1-128)*33);
  const float twv = w1src[0];
  const float b1v = (r1 < 128) ? fb1[r1] : gb1[r1-128];
  h8 w1z[2];
  #pragma unroll
  for (int c = 0; c < 2; ++c) {      // stride-33 rows: scalar loads (startup only)
    h8 w;
    #pragma unroll
    for (int e = 0; e < 8; ++e) w[e] = (f16)w1src[1 + k1*16 + c*8 + e];
    w1z[c] = w;
  }
  const int ch1 = (r1 < 128) ? (r1 >> 3) : ((r1 - 128) >> 3);
  const int sl1 = (r1 < 128) ? ((ch1 & 3)*4 + (ch1 >> 2))
                             : (16 + (ch1 & 1)*8 + (ch1 >> 1));
  // --- P2 role ---
  const int j2 = t >> 2, kq = t & 3;
  const float b2v = fb2[j2];
  h8 w2[4];
  {
    const float* p2 = fW2 + j2*H_ + kq*32;
    #pragma unroll
    for (int c = 0; c < 4; ++c) w2[c] = ld8(p2 + c*8);
  }
  const int n2  = j2 >> 3;
  const int sl2 = 34 + (n2 & 1)*8 + (n2 >> 1);
  // --- P3 role ---
  const int o3 = t >> 3, ke = t & 7;
  const int sel = o3 & 1, zi = o3 >> 1;
  h8 w3[2];
  {
    const float* p3 = (sel ? (gW2 + zi*H_) : (fW3 + zi*H_)) + ke*16;
    #pragma unroll
    for (int c = 0; c < 2; ++c) w3[c] = ld8(p3 + c*8);
  }
  const float b3v = sel ? gb2[zi] : fb3[zi];
  const int rg3 = sel ? 16 : 34;
  const bool zmaster = ((t & 15) == 0);   // sel==0, ke==0
  // --- proj role (t<128) ---
  const int pd = t >> 1, kp = t & 1;
  h8 pw[2];
  float pbv = 0.f;
  if (t < 128) {
    const float* pp = pW + pd*Z_ + kp*16;
    pw[0] = ld8(pp);
    pw[1] = ld8(pp + 8);
    pbv = pb[pd];
  }

  for (int i = t; i < 515; i += 512) tsL[i] = ts[i];
  float zm0 = 0.f, zm1 = 0.f;            // fp32 z masters at t%16==0 lanes
  if (zmaster) {
    zm0 = z0[(b0+0)*Z_ + zi];
    zm1 = z0[(b0+1)*Z_ + zi];
    ((f16*)zcB)[ 0 + zi] = (f16)zm0;
    ((f16*)zcB)[32 + zi] = (f16)zm1;
  }
  float loss = 0.f;
  __syncthreads();

  #pragma unroll 1
  for (int l = 0; l < NSTEP; ++l) {
    const float tl  = tsL[l];
    const float dt  = tsL[l+1] - tl;
    const float sdt = sqrtf(dt);
    const int ln = l + 1;
    const bool ev = ((ln & 1) == 0) && ln >= 2 && ln <= 512;
    const bool od = ((ln & 1) == 1) && ln >= 3 && ln <= 511;
    float dw0 = 0.f, dw1 = 0.f;
    if (zmaster) {
      dw0 = dW[(l*B_ + b0    )*Z_ + zi];
      dw1 = dW[(l*B_ + b0 + 1)*Z_ + zi];
    }
    float xv0 = 0.f, xv1 = 0.f;
    if (ev && t < 128 && kp == 0) {
      xv0 = xs[(((ln-2)>>1)*B_ + b0    )*D_ + pd];
      xv1 = xs[(((ln-2)>>1)*B_ + b0 + 1)*D_ + pd];
    }

    // phase 1: h1/gh = relu([t,z] @ W1.T + b); half-z per lane, both batches
    {
      float p0 = dot8(zcB[0][k1*2    ], w1z[0], 0.f);
      float p1 = dot8(zcB[1][k1*2    ], w1z[0], 0.f);
      p0 = dot8(zcB[0][k1*2 + 1], w1z[1], p0);
      p1 = dot8(zcB[1][k1*2 + 1], w1z[1], p1);
      p0 += __shfl_xor(p0, 1, 64);
      p1 += __shfl_xor(p1, 1, 64);
      if (k1 == 0) {
        float base = fmaf(twv, tl, b1v);
        float a0 = fmaxf(p0 + base, 0.f);
        float a1 = fmaxf(p1 + base, 0.f);
        ((f16*)hA)[(  0 + sl1)*8 + (r1 & 7)] = (f16)a0;
        ((f16*)hA)[(50 + sl1)*8 + (r1 & 7)] = (f16)a1;
      }
    }
    __syncthreads();   // A

    // phase 2: h2 = relu(h1 @ fW2.T + b2); quarter-k per lane, both batches
    {
      float a0 = dot8(hA[0][0*4 + kq], w2[0], 0.f);
      float c0 = dot8(hA[0][1*4 + kq], w2[1], 0.f);
      float a1 = dot8(hA[1][0*4 + kq], w2[0], 0.f);
      float c1 = dot8(hA[1][1*4 + kq], w2[1], 0.f);
      a0 = dot8(hA[0][2*4 + kq], w2[2], a0);
      c0 = dot8(hA[0][3*4 + kq], w2[3], c0);
      a1 = dot8(hA[1][2*4 + kq], w2[2], a1);
      c1 = dot8(hA[1][3*4 + kq], w2[3], c1);
      float q0 = a0 + c0, q1 = a1 + c1;
      q0 += __shfl_xor(q0, 1, 64);  q0 += __shfl_xor(q0, 2, 64);
      q1 += __shfl_xor(q1, 1, 64);  q1 += __shfl_xor(q1, 2, 64);
      if (kq == 0) {
        float h20 = fmaxf(q0 + b2v, 0.f);
        float h21 = fmaxf(q1 + b2v, 0.f);
        ((f16*)hA)[(  0 + sl2)*8 + (j2 & 7)] = (f16)h20;
        ((f16*)hA)[(50 + sl2)*8 + (j2 & 7)] = (f16)h21;
      }
    }
    __syncthreads();   // B

    // phase 3: drift/diff eighth-k dots; butterfly over ke; shfl_xor(8)
    // exchanges drift<->diff; zmaster updates both batches' z.
    {
      float q0 = dot8(hA[0][rg3     + ke], w3[0], 0.f);
      float q1 = dot8(hA[1][rg3     + ke], w3[0], 0.f);
      q0 = dot8(hA[0][rg3 + 8 + ke], w3[1], q0);
      q1 = dot8(hA[1][rg3 + 8 + ke], w3[1], q1);
      q0 += __shfl_xor(q0, 1, 64); q0 += __shfl_xor(q0, 2, 64); q0 += __shfl_xor(q0, 4, 64);
      q1 += __shfl_xor(q1, 1, 64); q1 += __shfl_xor(q1, 2, 64); q1 += __shfl_xor(q1, 4, 64);
      q0 += b3v;
      q1 += b3v;
      float o0 = __shfl_xor(q0, 8, 64);   // drift lanes get diff, vice versa
      float o1 = __shfl_xor(q1, 8, 64);
      if (zmaster) {                      // sel==0: q=drift, o=diff
        zm0 += q0*dt + o0*(sdt*dw0);
        zm1 += q1*dt + o1*(sdt*dw1);
        ((f16*)zcB)[ 0 + zi] = (f16)zm0;
        ((f16*)zcB)[32 + zi] = (f16)zm1;
      }
    }
    __syncthreads();   // C

    // fused projection (waves 0,1) on needed steps; half-z per lane
    if ((ev || od) && t < 128) {
      float q0 = dot8(zcB[0][kp*2    ], pw[0], 0.f);
      float q1 = dot8(zcB[1][kp*2    ], pw[0], 0.f);
      q0 = dot8(zcB[0][kp*2 + 1], pw[1], q0);
      q1 = dot8(zcB[1][kp*2 + 1], pw[1], q1);
      q0 += __shfl_xor(q0, 1, 64);
      q1 += __shfl_xor(q1, 1, 64);
      if (kp == 0) {
        float acc0 = q0 + pbv, acc1 = q1 + pbv;
        if (ev) {
          float d0 = acc0 - xv0; loss = fmaf(d0, d0, loss);
          float d1 = acc1 - xv1; loss = fmaf(d1, d1, loss);
        } else {
          out[2 + (((ln-3)>>1)*B_ + b0    )*D_ + pd] = acc0;
          out[2 + (((ln-3)>>1)*B_ + b0 + 1)*D_ + pd] = acc1;
        }
      }
    }
  }

  if (t < 128) {
    #pragma unroll
    for (int s2 = 32; s2 > 0; s2 >>= 1) loss += __shfl_down(loss, s2, 64);
    if (t == 0)  lred[0] = loss;
    if (t == 64) lred[1] = loss;
  }
  __syncthreads();
  if (t == 0) atomicAdd(out + 0, (lred[0] + lred[1]) * (1.f/16777216.f));
}

extern "C" void kernel_launch(void* const* d_in, const int* in_sizes, int n_in,
                              void* d_out, int out_size, void* d_ws, size_t ws_size,
                              hipStream_t stream) {
  (void)in_sizes; (void)n_in; (void)out_size; (void)ws_size;
  const float* xs   = (const float*)d_in[0];
  const float* ts   = (const float*)d_in[1];
  const float* eps  = (const float*)d_in[2];
  const float* dWp  = (const float*)d_in[3];
  const float* Wih  = (const float*)d_in[4];
  const float* Whh  = (const float*)d_in[5];
  const float* bih  = (const float*)d_in[6];
  const float* bhh  = (const float*)d_in[7];
  const float* encW = (const float*)d_in[8];
  const float* encB = (const float*)d_in[9];
  const float* qW   = (const float*)d_in[10];
  const float* qB   = (const float*)d_in[11];
  const float* fW1  = (const float*)d_in[12];
  const float* fb1  = (const float*)d_in[13];
  const float* fW2  = (const float*)d_in[14];
  const float* fb2  = (const float*)d_in[15];
  const float* fW3  = (const float*)d_in[16];
  const float* fb3  = (const float*)d_in[17];
  const float* gW1  = (const float*)d_in[18];
  const float* gb1  = (const float*)d_in[19];
  const float* gW2  = (const float*)d_in[20];
  const float* gb2  = (const float*)d_in[21];
  const float* pW   = (const float*)d_in[22];
  const float* pb   = (const float*)d_in[23];
  const float* pm   = (const float*)d_in[24];
  const float* pls  = (const float*)d_in[25];

  float* out = (float*)d_out;
  float* ws  = (float*)d_ws;
  float* hT = ws;              // 1024*128 floats
  float* z0 = ws + 131072;     // 1024*32 floats

  hipMemsetAsync(d_out, 0, 2*sizeof(float), stream);
  hipLaunchKernelGGL(gru_kernel, dim3(512), dim3(256), 0, stream,
                     xs, Wih, Whh, bih, bhh, hT);
  hipLaunchKernelGGL(enc_kernel, dim3(256), dim3(256), 0, stream,
                     hT, encW, encB, qW, qB, eps, pm, pls, z0, out);
  hipLaunchKernelGGL(sde_kernel, dim3(512), dim3(512), 0, stream,
                     z0, ts, dWp, xs, fW1, fb1, fW2, fb2, fW3, fb3,
                     gW1, gb1, gW2, gb2, pW, pb, out);
}